// Round 1
// baseline (5664.824 us; speedup 1.0000x reference)
//
#include <hip/hip_runtime.h>
#include <math.h>

// Problem constants (fixed by the reference)
#define NN   100000
#define FIN  1024
#define HIDN 16
#define CCH  64
#define EE   3200000
#define BNEPS 1e-5f

// ---------------------------------------------------------------------------
// k_deg: count in-degree (dst side only; self-loop added as +1 in k_dis)
// ---------------------------------------------------------------------------
__global__ __launch_bounds__(256) void k_deg(const int* __restrict__ ei,
                                             unsigned* __restrict__ deg) {
  int e = blockIdx.x * 256 + threadIdx.x;
  if (e < EE) atomicAdd(&deg[ei[EE + e]], 1u);
}

__global__ __launch_bounds__(256) void k_dis(const unsigned* __restrict__ deg,
                                             float* __restrict__ dis) {
  int i = blockIdx.x * 256 + threadIdx.x;
  if (i < NN) dis[i] = rsqrtf((float)(deg[i] + 1u));
}

// ---------------------------------------------------------------------------
// k_gemm1: xw1[N,16] = x[N,1024] @ w1[1024,16]; also h1 = xw1 * dis^2 (self loop)
// Wave computes 4 rows at a time. w1 lives in LDS (64KB) with quad swizzle.
// Lane owns k = i*64+lane; butterfly transpose-reduce leaves lane l with
// output (row = l>>4, col = l&15).
// ---------------------------------------------------------------------------
#define G1_ROWS_PER_BLOCK 128   // 4 waves * 32 rows
__global__ __launch_bounds__(256, 2) void k_gemm1(const float* __restrict__ x,
                                                  const float* __restrict__ w1,
                                                  const float* __restrict__ dis,
                                                  float* __restrict__ xw1,
                                                  float* __restrict__ h1) {
  __shared__ __align__(16) float w1s[1024 * 16];
  for (int idx = threadIdx.x; idx < 1024 * 16; idx += 256) {
    int k = idx >> 4, j = idx & 15;
    int p = (j >> 2) ^ ((k >> 1) & 3);          // quad swizzle -> conflict-free reads
    w1s[(k << 4) + (p << 2) + (j & 3)] = w1[idx];
  }
  __syncthreads();

  const int lane = threadIdx.x & 63;
  const int wave = threadIdx.x >> 6;
  const int sw = (lane >> 1) & 3;               // (k>>1)&3 with k = i*64+lane
  const int wave_row0 = blockIdx.x * G1_ROWS_PER_BLOCK + wave * 32;

  for (int g = 0; g < 8; ++g) {
    int row0 = wave_row0 + g * 4;               // uniform per wave
    if (row0 >= NN) break;
    int r0 = row0;
    int r1 = min(row0 + 1, NN - 1);
    int r2 = min(row0 + 2, NN - 1);
    int r3 = min(row0 + 3, NN - 1);

    float acc[64];
#pragma unroll
    for (int t = 0; t < 64; ++t) acc[t] = 0.0f;

#pragma unroll
    for (int i = 0; i < 16; ++i) {
      int k = i * 64 + lane;
      float xv0 = x[(size_t)r0 * FIN + k];
      float xv1 = x[(size_t)r1 * FIN + k];
      float xv2 = x[(size_t)r2 * FIN + k];
      float xv3 = x[(size_t)r3 * FIN + k];
      const float* wr = &w1s[k << 4];
#pragma unroll
      for (int q = 0; q < 4; ++q) {
        float4 wq = *(const float4*)(wr + ((q ^ sw) << 2));
        int b = q * 4;
        acc[b + 0]      += xv0 * wq.x;
        acc[b + 1]      += xv0 * wq.y;
        acc[b + 2]      += xv0 * wq.z;
        acc[b + 3]      += xv0 * wq.w;
        acc[16 + b + 0] += xv1 * wq.x;
        acc[16 + b + 1] += xv1 * wq.y;
        acc[16 + b + 2] += xv1 * wq.z;
        acc[16 + b + 3] += xv1 * wq.w;
        acc[32 + b + 0] += xv2 * wq.x;
        acc[32 + b + 1] += xv2 * wq.y;
        acc[32 + b + 2] += xv2 * wq.z;
        acc[32 + b + 3] += xv2 * wq.w;
        acc[48 + b + 0] += xv3 * wq.x;
        acc[48 + b + 1] += xv3 * wq.y;
        acc[48 + b + 2] += xv3 * wq.z;
        acc[48 + b + 3] += xv3 * wq.w;
      }
    }

    // recursive-halving butterfly: lane l ends with sum over lanes of acc[l]
#pragma unroll
    for (int o = 32; o >= 1; o >>= 1) {
      bool up = (lane & o) != 0;
#pragma unroll
      for (int t = 0; t < o; ++t) {
        float send = up ? acc[t] : acc[t + o];
        float recv = __shfl_xor(send, o, 64);
        float keep = up ? acc[t + o] : acc[t];
        acc[t] = keep + recv;
      }
    }

    int r = lane >> 4, j = lane & 15;
    int grow = row0 + r;
    if (grow < NN) {
      float v = acc[0];
      float d = dis[grow];
      xw1[grow * HIDN + j] = v;
      h1[grow * HIDN + j] = v * d * d;   // self-loop contribution (norm = dis^2)
    }
  }
}

// ---------------------------------------------------------------------------
// k_edge: per-edge gather (16 floats) * norm, atomic scatter-add to dst
// used twice: (xw1 -> h1) and (relu_h1 -> agg2)
// ---------------------------------------------------------------------------
__global__ __launch_bounds__(256) void k_edge(const int* __restrict__ ei,
                                              const float* __restrict__ dis,
                                              const float* __restrict__ sf,
                                              float* __restrict__ da) {
  int e = blockIdx.x * 256 + threadIdx.x;
  if (e >= EE) return;
  int s = ei[e];
  int d = ei[EE + e];
  float nr = dis[s] * dis[d];
  const float4* sp = (const float4*)(sf + (size_t)s * HIDN);
  float4 a = sp[0], b = sp[1], c = sp[2], dd = sp[3];
  float* op = da + (size_t)d * HIDN;
  atomicAdd(op + 0,  a.x * nr);  atomicAdd(op + 1,  a.y * nr);
  atomicAdd(op + 2,  a.z * nr);  atomicAdd(op + 3,  a.w * nr);
  atomicAdd(op + 4,  b.x * nr);  atomicAdd(op + 5,  b.y * nr);
  atomicAdd(op + 6,  b.z * nr);  atomicAdd(op + 7,  b.w * nr);
  atomicAdd(op + 8,  c.x * nr);  atomicAdd(op + 9,  c.y * nr);
  atomicAdd(op + 10, c.z * nr);  atomicAdd(op + 11, c.w * nr);
  atomicAdd(op + 12, dd.x * nr); atomicAdd(op + 13, dd.y * nr);
  atomicAdd(op + 14, dd.z * nr); atomicAdd(op + 15, dd.w * nr);
}

// ---------------------------------------------------------------------------
// k_postagg1: relu_h1 = relu(h1 + b1); agg2 = relu_h1 * dis^2 (self-loop init)
// ---------------------------------------------------------------------------
__global__ __launch_bounds__(256) void k_postagg1(const float* __restrict__ h1,
                                                  const float* __restrict__ b1,
                                                  const float* __restrict__ dis,
                                                  float* __restrict__ rh1,
                                                  float* __restrict__ agg2) {
  int idx = blockIdx.x * 256 + threadIdx.x;
  if (idx >= NN * HIDN) return;
  int i = idx >> 4, j = idx & 15;
  float r = fmaxf(h1[idx] + b1[j], 0.0f);
  rh1[idx] = r;
  float d = dis[i];
  agg2[idx] = r * d * d;
}

// ---------------------------------------------------------------------------
// k_fuse2: per row (one wave): h2 = agg2@w2 + b2 -> log_softmax ->
//          * exp(weight_raw) -> @mlp_w + mlp_b -> write d_out,
//          accumulate per-channel sum/sumsq for BN.
// ---------------------------------------------------------------------------
__global__ __launch_bounds__(256) void k_fuse2(const float* __restrict__ agg2,
                                               const float* __restrict__ w2,
                                               const float* __restrict__ b2,
                                               const float* __restrict__ mlpw,
                                               const float* __restrict__ mlpb,
                                               const float* __restrict__ wraw,
                                               float* __restrict__ out,
                                               float* __restrict__ gsum,
                                               float* __restrict__ gsq) {
  __shared__ float w2s[HIDN * CCH];
  __shared__ float mlps[CCH * CCH];
  __shared__ float reds[256];
  __shared__ float redq[256];
  for (int idx = threadIdx.x; idx < HIDN * CCH; idx += 256) w2s[idx] = w2[idx];
  for (int idx = threadIdx.x; idx < CCH * CCH; idx += 256) mlps[idx] = mlpw[idx];
  __syncthreads();

  const int lane = threadIdx.x & 63;
  const int wave = threadIdx.x >> 6;
  const int j = lane;
  const float b2j = b2[j];
  const float mbj = mlpb[j];
  const int gw = blockIdx.x * 4 + wave;
  const int nw = gridDim.x * 4;

  float sum = 0.0f, sq = 0.0f;
  for (int i = gw; i < NN; i += nw) {
    float av = agg2[(size_t)i * HIDN + (lane & 15)];
    float h2 = b2j;
#pragma unroll
    for (int k = 0; k < HIDN; ++k)
      h2 = fmaf(__shfl(av, k, 64), w2s[k * CCH + j], h2);

    float mx = h2;
#pragma unroll
    for (int o = 32; o >= 1; o >>= 1) mx = fmaxf(mx, __shfl_xor(mx, o, 64));
    float ex = __expf(h2 - mx);
    float se = ex;
#pragma unroll
    for (int o = 32; o >= 1; o >>= 1) se += __shfl_xor(se, o, 64);
    float lsm = h2 - mx - __logf(se);

    float g = __expf(wraw[i]) * lsm;

    float m = mbj;
#pragma unroll
    for (int c = 0; c < CCH; ++c)
      m = fmaf(__shfl(g, c, 64), mlps[c * CCH + j], m);

    out[(size_t)i * CCH + j] = m;
    sum += m;
    sq = fmaf(m, m, sq);
  }

  reds[threadIdx.x] = sum;
  redq[threadIdx.x] = sq;
  __syncthreads();
  if (threadIdx.x < 64) {
    float s = reds[threadIdx.x] + reds[threadIdx.x + 64] +
              reds[threadIdx.x + 128] + reds[threadIdx.x + 192];
    float q = redq[threadIdx.x] + redq[threadIdx.x + 64] +
              redq[threadIdx.x + 128] + redq[threadIdx.x + 192];
    atomicAdd(&gsum[threadIdx.x], s);
    atomicAdd(&gsq[threadIdx.x], q);
  }
}

// ---------------------------------------------------------------------------
// k_stats: finalize BN params (1 block, 64 threads)
// ---------------------------------------------------------------------------
__global__ void k_stats(const float* __restrict__ gsum,
                        const float* __restrict__ gsq,
                        const float* __restrict__ gamma,
                        const float* __restrict__ beta,
                        float* __restrict__ bnp) {
  int j = threadIdx.x;
  if (j >= CCH) return;
  const float inv_n = 1.0f / (float)NN;
  float mean = gsum[j] * inv_n;
  float var = gsq[j] * inv_n - mean * mean;
  float sc = rsqrtf(var + BNEPS) * gamma[j];
  bnp[j] = mean;
  bnp[CCH + j] = sc;
  bnp[2 * CCH + j] = beta[j];
}

// ---------------------------------------------------------------------------
// k_out: BN apply + final log_softmax, in-place on d_out (wave per row)
// ---------------------------------------------------------------------------
__global__ __launch_bounds__(256) void k_out(float* __restrict__ out,
                                             const float* __restrict__ bnp) {
  const int lane = threadIdx.x & 63;
  const int wave = threadIdx.x >> 6;
  const int j = lane;
  const float mean = bnp[j];
  const float sc = bnp[CCH + j];
  const float bt = bnp[2 * CCH + j];
  const int gw = blockIdx.x * 4 + wave;
  const int nw = gridDim.x * 4;
  for (int i = gw; i < NN; i += nw) {
    float m = out[(size_t)i * CCH + j];
    float y = fmaf(m - mean, sc, bt);
    float mx = y;
#pragma unroll
    for (int o = 32; o >= 1; o >>= 1) mx = fmaxf(mx, __shfl_xor(mx, o, 64));
    float ex = __expf(y - mx);
    float se = ex;
#pragma unroll
    for (int o = 32; o >= 1; o >>= 1) se += __shfl_xor(se, o, 64);
    out[(size_t)i * CCH + j] = y - mx - __logf(se);
  }
}

// ---------------------------------------------------------------------------
extern "C" void kernel_launch(void* const* d_in, const int* in_sizes, int n_in,
                              void* d_out, int out_size, void* d_ws, size_t ws_size,
                              hipStream_t stream) {
  const float* x     = (const float*)d_in[0];
  const int*   ei    = (const int*)d_in[1];
  const float* w1    = (const float*)d_in[2];
  const float* b1    = (const float*)d_in[3];
  const float* w2    = (const float*)d_in[4];
  const float* b2    = (const float*)d_in[5];
  const float* mlpw  = (const float*)d_in[6];
  const float* mlpb  = (const float*)d_in[7];
  const float* gamma = (const float*)d_in[8];
  const float* beta  = (const float*)d_in[9];
  const float* wraw  = (const float*)d_in[10];
  float* out = (float*)d_out;

  // workspace carve (256B aligned slots)
  char* w = (char*)d_ws;
  size_t off = 0;
  auto take = [&](size_t bytes) -> void* {
    void* p = w + off;
    off = (off + bytes + 255) & ~(size_t)255;
    return p;
  };
  unsigned* deg = (unsigned*)take((size_t)NN * 4);
  float* dis  = (float*)take((size_t)NN * 4);
  float* xw1  = (float*)take((size_t)NN * HIDN * 4);
  float* h1   = (float*)take((size_t)NN * HIDN * 4);
  float* rh1  = (float*)take((size_t)NN * HIDN * 4);
  float* agg2 = (float*)take((size_t)NN * HIDN * 4);
  float* gsum = (float*)take(CCH * 4);
  float* gsq  = (float*)take(CCH * 4);
  float* bnp  = (float*)take(3 * CCH * 4);
  (void)ws_size; (void)n_in; (void)in_sizes; (void)out_size;

  hipMemsetAsync(deg, 0, (size_t)NN * 4, stream);
  hipMemsetAsync(gsum, 0, CCH * 4, stream);
  hipMemsetAsync(gsq, 0, CCH * 4, stream);

  k_deg<<<(EE + 255) / 256, 256, 0, stream>>>(ei, deg);
  k_dis<<<(NN + 255) / 256, 256, 0, stream>>>(deg, dis);
  k_gemm1<<<(NN + G1_ROWS_PER_BLOCK - 1) / G1_ROWS_PER_BLOCK, 256, 0, stream>>>(
      x, w1, dis, xw1, h1);
  k_edge<<<(EE + 255) / 256, 256, 0, stream>>>(ei, dis, xw1, h1);
  k_postagg1<<<(NN * HIDN + 255) / 256, 256, 0, stream>>>(h1, b1, dis, rh1, agg2);
  k_edge<<<(EE + 255) / 256, 256, 0, stream>>>(ei, dis, rh1, agg2);
  k_fuse2<<<1024, 256, 0, stream>>>(agg2, w2, b2, mlpw, mlpb, wraw, out, gsum, gsq);
  k_stats<<<1, 64, 0, stream>>>(gsum, gsq, gamma, beta, bnp);
  k_out<<<1024, 256, 0, stream>>>(out, bnp);
}

// Round 2
// 766.474 us; speedup vs baseline: 7.3908x; 7.3908x over previous
//
#include <hip/hip_runtime.h>
#include <math.h>

// Problem constants (fixed by the reference)
#define NN   100000
#define FIN  1024
#define HIDN 16
#define CCH  64
#define EE   3200000
#define BNEPS 1e-5f
#define NB   ((NN + 255) / 256)   // 391 scan blocks

// ---------------------------------------------------------------------------
// k_deg: in-degree histogram (dst side only; self-loop +1 folded into k_dis)
// ---------------------------------------------------------------------------
__global__ __launch_bounds__(256) void k_deg(const int* __restrict__ ei,
                                             unsigned* __restrict__ deg) {
  int e = blockIdx.x * 256 + threadIdx.x;
  if (e < EE) atomicAdd(&deg[ei[EE + e]], 1u);
}

__global__ __launch_bounds__(256) void k_dis(const unsigned* __restrict__ deg,
                                             float* __restrict__ dis) {
  int i = blockIdx.x * 256 + threadIdx.x;
  if (i < NN) dis[i] = rsqrtf((float)(deg[i] + 1u));
}

// ---------------------------------------------------------------------------
// exclusive scan of deg -> rowptr (3 kernels: per-block, block-offsets, final)
// ---------------------------------------------------------------------------
__global__ __launch_bounds__(256) void k_scan_part(const unsigned* __restrict__ deg,
                                                   unsigned* __restrict__ exc,
                                                   unsigned* __restrict__ bsum) {
  __shared__ unsigned s[256];
  int t = threadIdx.x, i = blockIdx.x * 256 + t;
  unsigned v = (i < NN) ? deg[i] : 0u;
  s[t] = v;
  __syncthreads();
#pragma unroll
  for (int off = 1; off < 256; off <<= 1) {
    unsigned u = (t >= off) ? s[t - off] : 0u;
    __syncthreads();
    s[t] += u;
    __syncthreads();
  }
  if (i < NN) exc[i] = s[t] - v;
  if (t == 255) bsum[blockIdx.x] = s[255];
}

__global__ __launch_bounds__(512) void k_scan_boff(const unsigned* __restrict__ bsum,
                                                   unsigned* __restrict__ boff) {
  __shared__ unsigned s[512];
  int t = threadIdx.x;
  unsigned v = (t < NB) ? bsum[t] : 0u;
  s[t] = v;
  __syncthreads();
#pragma unroll
  for (int off = 1; off < 512; off <<= 1) {
    unsigned u = (t >= off) ? s[t - off] : 0u;
    __syncthreads();
    s[t] += u;
    __syncthreads();
  }
  if (t < NB) boff[t] = s[t] - v;
}

__global__ __launch_bounds__(256) void k_scan_final(const unsigned* __restrict__ exc,
                                                    const unsigned* __restrict__ boff,
                                                    int* __restrict__ rowptr,
                                                    int* __restrict__ cur) {
  int i = blockIdx.x * 256 + threadIdx.x;
  if (i < NN) {
    int r = (int)(boff[i >> 8] + exc[i]);
    rowptr[i] = r;
    cur[i] = r;
  } else if (i == NN) {
    rowptr[NN] = EE;
  }
}

// ---------------------------------------------------------------------------
// k_scatter: bucket edges by dst; perm[slot] = src  (1 int atomic per edge)
// ---------------------------------------------------------------------------
__global__ __launch_bounds__(256) void k_scatter(const int* __restrict__ ei,
                                                 int* __restrict__ cur,
                                                 int* __restrict__ perm) {
  int e = blockIdx.x * 256 + threadIdx.x;
  if (e >= EE) return;
  int s = ei[e];
  int d = ei[EE + e];
  int pos = atomicAdd(&cur[d], 1);
  perm[pos] = s;
}

// ---------------------------------------------------------------------------
// k_gemm1: xw1[N,16] = x[N,1024] @ w1[1024,16]
// Wave computes 4 rows at a time; w1 in LDS (64KB, quad-swizzled);
// butterfly transpose-reduce leaves lane l with (row l>>4, col l&15).
// ---------------------------------------------------------------------------
#define G1_ROWS_PER_BLOCK 128   // 4 waves * 32 rows
__global__ __launch_bounds__(256, 2) void k_gemm1(const float* __restrict__ x,
                                                  const float* __restrict__ w1,
                                                  float* __restrict__ xw1) {
  __shared__ __align__(16) float w1s[1024 * 16];
  for (int idx = threadIdx.x; idx < 1024 * 16; idx += 256) {
    int k = idx >> 4, j = idx & 15;
    int p = (j >> 2) ^ ((k >> 1) & 3);          // quad swizzle -> conflict-free
    w1s[(k << 4) + (p << 2) + (j & 3)] = w1[idx];
  }
  __syncthreads();

  const int lane = threadIdx.x & 63;
  const int wave = threadIdx.x >> 6;
  const int sw = (lane >> 1) & 3;
  const int wave_row0 = blockIdx.x * G1_ROWS_PER_BLOCK + wave * 32;

  for (int g = 0; g < 8; ++g) {
    int row0 = wave_row0 + g * 4;
    if (row0 >= NN) break;
    int r0 = row0;
    int r1 = min(row0 + 1, NN - 1);
    int r2 = min(row0 + 2, NN - 1);
    int r3 = min(row0 + 3, NN - 1);

    float acc[64];
#pragma unroll
    for (int t = 0; t < 64; ++t) acc[t] = 0.0f;

#pragma unroll
    for (int i = 0; i < 16; ++i) {
      int k = i * 64 + lane;
      float xv0 = x[(size_t)r0 * FIN + k];
      float xv1 = x[(size_t)r1 * FIN + k];
      float xv2 = x[(size_t)r2 * FIN + k];
      float xv3 = x[(size_t)r3 * FIN + k];
      const float* wr = &w1s[k << 4];
#pragma unroll
      for (int q = 0; q < 4; ++q) {
        float4 wq = *(const float4*)(wr + ((q ^ sw) << 2));
        int b = q * 4;
        acc[b + 0]      += xv0 * wq.x;
        acc[b + 1]      += xv0 * wq.y;
        acc[b + 2]      += xv0 * wq.z;
        acc[b + 3]      += xv0 * wq.w;
        acc[16 + b + 0] += xv1 * wq.x;
        acc[16 + b + 1] += xv1 * wq.y;
        acc[16 + b + 2] += xv1 * wq.z;
        acc[16 + b + 3] += xv1 * wq.w;
        acc[32 + b + 0] += xv2 * wq.x;
        acc[32 + b + 1] += xv2 * wq.y;
        acc[32 + b + 2] += xv2 * wq.z;
        acc[32 + b + 3] += xv2 * wq.w;
        acc[48 + b + 0] += xv3 * wq.x;
        acc[48 + b + 1] += xv3 * wq.y;
        acc[48 + b + 2] += xv3 * wq.z;
        acc[48 + b + 3] += xv3 * wq.w;
      }
    }

#pragma unroll
    for (int o = 32; o >= 1; o >>= 1) {
      bool up = (lane & o) != 0;
#pragma unroll
      for (int t = 0; t < o; ++t) {
        float send = up ? acc[t] : acc[t + o];
        float recv = __shfl_xor(send, o, 64);
        float keep = up ? acc[t + o] : acc[t];
        acc[t] = keep + recv;
      }
    }

    int r = lane >> 4, j = lane & 15;
    int grow = row0 + r;
    if (grow < NN) xw1[grow * HIDN + j] = acc[0];
  }
}

// ---------------------------------------------------------------------------
// k_agg: CSR gather-reduce aggregation (replaces atomic scatter).
//   16 lanes per node, lane = channel j. Per edge: coalesced 64B gather.
//   out_i = dis_i * (sum_{e} sf[perm[e]]*dis[perm[e]] + sf[i]*dis_i)
//   MODE 0: out = relu(v + b1[j])   (conv1 epilogue)
//   MODE 1: out = v                 (conv2 pre-GEMM aggregate)
// ---------------------------------------------------------------------------
template <int MODE>
__global__ __launch_bounds__(256) void k_agg(const int* __restrict__ rowptr,
                                             const int* __restrict__ perm,
                                             const float* __restrict__ dis,
                                             const float* __restrict__ sf,
                                             const float* __restrict__ b1,
                                             float* __restrict__ out) {
  int g = (blockIdx.x * 256 + threadIdx.x) >> 4;   // node
  int j = threadIdx.x & 15;                        // channel
  if (g >= NN) return;
  int beg = rowptr[g], end = rowptr[g + 1];
  float acc0 = 0.0f, acc1 = 0.0f;
  int e = beg;
  for (; e + 1 < end; e += 2) {
    int s0 = perm[e], s1 = perm[e + 1];
    acc0 = fmaf(sf[(size_t)s0 * HIDN + j], dis[s0], acc0);
    acc1 = fmaf(sf[(size_t)s1 * HIDN + j], dis[s1], acc1);
  }
  if (e < end) {
    int s0 = perm[e];
    acc0 = fmaf(sf[(size_t)s0 * HIDN + j], dis[s0], acc0);
  }
  float di = dis[g];
  float v = di * (acc0 + acc1 + sf[(size_t)g * HIDN + j] * di);
  if (MODE == 0)
    out[(size_t)g * HIDN + j] = fmaxf(v + b1[j], 0.0f);
  else
    out[(size_t)g * HIDN + j] = v;
}

// ---------------------------------------------------------------------------
// k_fuse2: per row (one wave): h2 = agg2@w2 + b2 -> log_softmax ->
//          * exp(weight_raw) -> @mlp_w + mlp_b -> write d_out,
//          accumulate per-channel sum/sumsq for BN.
// ---------------------------------------------------------------------------
__global__ __launch_bounds__(256) void k_fuse2(const float* __restrict__ agg2,
                                               const float* __restrict__ w2,
                                               const float* __restrict__ b2,
                                               const float* __restrict__ mlpw,
                                               const float* __restrict__ mlpb,
                                               const float* __restrict__ wraw,
                                               float* __restrict__ out,
                                               float* __restrict__ gsum,
                                               float* __restrict__ gsq) {
  __shared__ float w2s[HIDN * CCH];
  __shared__ float mlps[CCH * CCH];
  __shared__ float reds[256];
  __shared__ float redq[256];
  for (int idx = threadIdx.x; idx < HIDN * CCH; idx += 256) w2s[idx] = w2[idx];
  for (int idx = threadIdx.x; idx < CCH * CCH; idx += 256) mlps[idx] = mlpw[idx];
  __syncthreads();

  const int lane = threadIdx.x & 63;
  const int wave = threadIdx.x >> 6;
  const int j = lane;
  const float b2j = b2[j];
  const float mbj = mlpb[j];
  const int gw = blockIdx.x * 4 + wave;
  const int nw = gridDim.x * 4;

  float sum = 0.0f, sq = 0.0f;
  for (int i = gw; i < NN; i += nw) {
    float av = agg2[(size_t)i * HIDN + (lane & 15)];
    float h2 = b2j;
#pragma unroll
    for (int k = 0; k < HIDN; ++k)
      h2 = fmaf(__shfl(av, k, 64), w2s[k * CCH + j], h2);

    float mx = h2;
#pragma unroll
    for (int o = 32; o >= 1; o >>= 1) mx = fmaxf(mx, __shfl_xor(mx, o, 64));
    float ex = __expf(h2 - mx);
    float se = ex;
#pragma unroll
    for (int o = 32; o >= 1; o >>= 1) se += __shfl_xor(se, o, 64);
    float lsm = h2 - mx - __logf(se);

    float g = __expf(wraw[i]) * lsm;

    float m = mbj;
#pragma unroll
    for (int c = 0; c < CCH; ++c)
      m = fmaf(__shfl(g, c, 64), mlps[c * CCH + j], m);

    out[(size_t)i * CCH + j] = m;
    sum += m;
    sq = fmaf(m, m, sq);
  }

  reds[threadIdx.x] = sum;
  redq[threadIdx.x] = sq;
  __syncthreads();
  if (threadIdx.x < 64) {
    float s = reds[threadIdx.x] + reds[threadIdx.x + 64] +
              reds[threadIdx.x + 128] + reds[threadIdx.x + 192];
    float q = redq[threadIdx.x] + redq[threadIdx.x + 64] +
              redq[threadIdx.x + 128] + redq[threadIdx.x + 192];
    atomicAdd(&gsum[threadIdx.x], s);
    atomicAdd(&gsq[threadIdx.x], q);
  }
}

// ---------------------------------------------------------------------------
__global__ void k_stats(const float* __restrict__ gsum,
                        const float* __restrict__ gsq,
                        const float* __restrict__ gamma,
                        const float* __restrict__ beta,
                        float* __restrict__ bnp) {
  int j = threadIdx.x;
  if (j >= CCH) return;
  const float inv_n = 1.0f / (float)NN;
  float mean = gsum[j] * inv_n;
  float var = gsq[j] * inv_n - mean * mean;
  float sc = rsqrtf(var + BNEPS) * gamma[j];
  bnp[j] = mean;
  bnp[CCH + j] = sc;
  bnp[2 * CCH + j] = beta[j];
}

// ---------------------------------------------------------------------------
// k_out: BN apply + final log_softmax, in-place on d_out (wave per row)
// ---------------------------------------------------------------------------
__global__ __launch_bounds__(256) void k_out(float* __restrict__ out,
                                             const float* __restrict__ bnp) {
  const int lane = threadIdx.x & 63;
  const int wave = threadIdx.x >> 6;
  const int j = lane;
  const float mean = bnp[j];
  const float sc = bnp[CCH + j];
  const float bt = bnp[2 * CCH + j];
  const int gw = blockIdx.x * 4 + wave;
  const int nw = gridDim.x * 4;
  for (int i = gw; i < NN; i += nw) {
    float m = out[(size_t)i * CCH + j];
    float y = fmaf(m - mean, sc, bt);
    float mx = y;
#pragma unroll
    for (int o = 32; o >= 1; o >>= 1) mx = fmaxf(mx, __shfl_xor(mx, o, 64));
    float ex = __expf(y - mx);
    float se = ex;
#pragma unroll
    for (int o = 32; o >= 1; o >>= 1) se += __shfl_xor(se, o, 64);
    out[(size_t)i * CCH + j] = y - mx - __logf(se);
  }
}

// ---------------------------------------------------------------------------
extern "C" void kernel_launch(void* const* d_in, const int* in_sizes, int n_in,
                              void* d_out, int out_size, void* d_ws, size_t ws_size,
                              hipStream_t stream) {
  const float* x     = (const float*)d_in[0];
  const int*   ei    = (const int*)d_in[1];
  const float* w1    = (const float*)d_in[2];
  const float* b1    = (const float*)d_in[3];
  const float* w2    = (const float*)d_in[4];
  const float* b2    = (const float*)d_in[5];
  const float* mlpw  = (const float*)d_in[6];
  const float* mlpb  = (const float*)d_in[7];
  const float* gamma = (const float*)d_in[8];
  const float* beta  = (const float*)d_in[9];
  const float* wraw  = (const float*)d_in[10];
  float* out = (float*)d_out;

  // workspace carve (256B aligned slots)
  char* w = (char*)d_ws;
  size_t off = 0;
  auto take = [&](size_t bytes) -> void* {
    void* p = w + off;
    off = (off + bytes + 255) & ~(size_t)255;
    return p;
  };
  unsigned* deg    = (unsigned*)take((size_t)NN * 4);
  float*    dis    = (float*)take((size_t)NN * 4);
  unsigned* exc    = (unsigned*)take((size_t)NN * 4);
  unsigned* bsum   = (unsigned*)take((size_t)NB * 4);
  unsigned* boff   = (unsigned*)take((size_t)NB * 4);
  int*      rowptr = (int*)take((size_t)(NN + 1) * 4);
  int*      cur    = (int*)take((size_t)NN * 4);
  int*      perm   = (int*)take((size_t)EE * 4);
  float*    xw1    = (float*)take((size_t)NN * HIDN * 4);
  float*    rh1    = (float*)take((size_t)NN * HIDN * 4);
  float*    agg2   = (float*)take((size_t)NN * HIDN * 4);
  float*    gsum   = (float*)take(CCH * 4);
  float*    gsq    = (float*)take(CCH * 4);
  float*    bnp    = (float*)take(3 * CCH * 4);
  (void)ws_size; (void)n_in; (void)in_sizes; (void)out_size;

  hipMemsetAsync(deg, 0, (size_t)NN * 4, stream);
  hipMemsetAsync(gsum, 0, CCH * 4, stream);
  hipMemsetAsync(gsq, 0, CCH * 4, stream);

  // CSR build
  k_deg<<<(EE + 255) / 256, 256, 0, stream>>>(ei, deg);
  k_dis<<<(NN + 255) / 256, 256, 0, stream>>>(deg, dis);
  k_scan_part<<<NB, 256, 0, stream>>>(deg, exc, bsum);
  k_scan_boff<<<1, 512, 0, stream>>>(bsum, boff);
  k_scan_final<<<(NN + 256) / 256 + 1, 256, 0, stream>>>(exc, boff, rowptr, cur);
  k_scatter<<<(EE + 255) / 256, 256, 0, stream>>>(ei, cur, perm);

  // dense transform + 2 aggregation passes
  k_gemm1<<<(NN + G1_ROWS_PER_BLOCK - 1) / G1_ROWS_PER_BLOCK, 256, 0, stream>>>(x, w1, xw1);
  k_agg<0><<<(NN * 16 + 255) / 256, 256, 0, stream>>>(rowptr, perm, dis, xw1, b1, rh1);
  k_agg<1><<<(NN * 16 + 255) / 256, 256, 0, stream>>>(rowptr, perm, dis, rh1, b1, agg2);

  // fused tail
  k_fuse2<<<1024, 256, 0, stream>>>(agg2, w2, b2, mlpw, mlpb, wraw, out, gsum, gsq);
  k_stats<<<1, 64, 0, stream>>>(gsum, gsq, gamma, beta, bnp);
  k_out<<<1024, 256, 0, stream>>>(out, bnp);
}